// Round 5
// baseline (199.068 us; speedup 1.0000x reference)
//
#include <hip/hip_runtime.h>
#include <hip/hip_bf16.h>

#define B_SZ 1024
#define S_SZ 512
#define H_SZ 768
#define K3H  2304   // 3*H
#define HID  512
#define NC   3
#define KSPLIT_HALF 1152
#define POOL_BLKS (B_SZ * 3)

typedef __attribute__((ext_vector_type(8)))  __bf16        bf16x8;
typedef __attribute__((ext_vector_type(16))) float         f32x16;
typedef __attribute__((ext_vector_type(8)))  unsigned short ushort8x;

__device__ __forceinline__ unsigned short f2bf(float f) {
    unsigned u = __builtin_bit_cast(unsigned, f);
    unsigned r = (u + 0x7fffu + ((u >> 16) & 1u)) >> 16;
    return (unsigned short)r;
}

// ---------------------------------------------------------------------------
// Kernel 1 (merged): blocks [0,3072) = masked-mean pool, one single-wave
// block per (batch row, third-of-H). blk = b*3 + cz so the 3 siblings of a
// row dispatch adjacently (DRAM page locality). Blocks [3072,3360) = W1
// f32->bf16 transpose (64x64 tiles) riding under the pool's memory shadow.
// Single-wave pool block: ballot compaction is fully lane-uniform (no
// reduce/broadcast needed).
// ---------------------------------------------------------------------------
__global__ __launch_bounds__(64) void pool_tr_kernel(
        const float* __restrict__ emb,          // [B,S,H] f32
        const int*   __restrict__ men,          // [B,S]
        const float* __restrict__ W1,           // [2304][512] f32
        unsigned short* __restrict__ o,         // [B,3H] bf16
        unsigned short* __restrict__ Bt)        // W1T [512][2304] bf16
{
    const int t   = threadIdx.x;
    const int blk = blockIdx.x;

    if (blk >= POOL_BLKS) {
        // ---- transpose path: 64x64 tile, 36 k-tiles x 8 n-tiles = 288 ----
        __shared__ unsigned short tile[64][65];
        const int bt = blk - POOL_BLKS;
        const int kb = (bt >> 3) * 64;
        const int nb = (bt & 7) * 64;
        #pragma unroll 4
        for (int r = 0; r < 64; ++r)
            tile[r][t] = f2bf(W1[(size_t)(kb + r) * HID + nb + t]);
        __syncthreads();
        #pragma unroll 4
        for (int r = 0; r < 64; ++r)
            Bt[(size_t)(nb + r) * K3H + kb + t] = tile[t][r];
        return;
    }

    // ---- pool path: b = blk/3, cz = blk%3 owns f4-columns [cz*64, cz*64+64)
    const int b  = blk / 3;
    const int cz = blk - b * 3;

    __shared__ unsigned short sel[S_SZ];        // s | (tag<<12)

    int basep = 0;
    int c0 = 0, c1 = 0, c2 = 0;
    const unsigned long long lt = (1ull << t) - 1ull;
    #pragma unroll
    for (int ch = 0; ch < 8; ++ch) {
        int s = ch * 64 + t;
        int m = men[(size_t)b * S_SZ + s];
        unsigned long long k2 = __ballot(m == 2);
        unsigned long long k3 = __ballot(m == 3);
        unsigned long long k4 = __ballot(m == 4);
        unsigned long long pk = k2 | k3 | k4;
        int pos = basep + __popcll(pk & lt);
        if (m >= 2) sel[pos] = (unsigned short)(s | ((m - 2) << 12));
        basep += __popcll(pk);
        c0 += __popcll(k2);
        c1 += __popcll(k3);
        c2 += __popcll(k4);
    }
    __syncthreads();

    const int ns = basep;                       // lane-uniform
    float4 a0 = {0.f,0.f,0.f,0.f}, a1 = {0.f,0.f,0.f,0.f}, a2 = {0.f,0.f,0.f,0.f};
    const float4* base =
        reinterpret_cast<const float4*>(emb + (size_t)b * S_SZ * H_SZ)
        + cz * 64 + t;

    #define ACCUM(E, V) do {                                             \
        int tg_ = (E) >> 12;                                             \
        if (tg_ == 0)      { a0.x+=V.x; a0.y+=V.y; a0.z+=V.z; a0.w+=V.w; } \
        else if (tg_ == 1) { a1.x+=V.x; a1.y+=V.y; a1.z+=V.z; a1.w+=V.w; } \
        else               { a2.x+=V.x; a2.y+=V.y; a2.z+=V.z; a2.w+=V.w; } \
    } while (0)

    int i = 0;
    for (; i + 4 <= ns; i += 4) {
        int e0 = sel[i], e1 = sel[i+1], e2 = sel[i+2], e3 = sel[i+3];
        float4 v0 = base[(e0 & 0x1ff) * 192];
        float4 v1 = base[(e1 & 0x1ff) * 192];
        float4 v2 = base[(e2 & 0x1ff) * 192];
        float4 v3 = base[(e3 & 0x1ff) * 192];
        ACCUM(e0, v0); ACCUM(e1, v1); ACCUM(e2, v2); ACCUM(e3, v3);
    }
    for (; i < ns; ++i) {
        int e = sel[i];
        float4 v = base[(e & 0x1ff) * 192];
        ACCUM(e, v);
    }
    #undef ACCUM

    const float r0 = 1.f / (float)c0;
    const float r1 = 1.f / (float)c1;
    const float r2 = 1.f / (float)c2;

    unsigned short* op = o + (size_t)b * K3H + cz * 256 + t * 4;
    ushort4 w0 = { f2bf(a0.x*r0), f2bf(a0.y*r0), f2bf(a0.z*r0), f2bf(a0.w*r0) };
    ushort4 w1 = { f2bf(a1.x*r1), f2bf(a1.y*r1), f2bf(a1.z*r1), f2bf(a1.w*r1) };
    ushort4 w2 = { f2bf(a2.x*r2), f2bf(a2.y*r2), f2bf(a2.z*r2), f2bf(a2.w*r2) };
    *reinterpret_cast<ushort4*>(op + 0 * H_SZ) = w0;
    *reinterpret_cast<ushort4*>(op + 1 * H_SZ) = w1;
    *reinterpret_cast<ushort4*>(op + 2 * H_SZ) = w2;
}

// ---------------------------------------------------------------------------
// Kernel 2: partial GEMM  hp[kz] = o @ W1T  over k-slice kz (no bias/relu).
// 64x64 tile, BK=64, 4 waves (2x2 of 32x32 mfma_f32_32x32x16_bf16),
// 2-phase reg-staged double buffer, XOR-swizzled LDS.
// Grid (8, 16, 2) = 256 blocks, 18 K-steps per block.
// ---------------------------------------------------------------------------
__global__ __launch_bounds__(256) void mlp1_kernel(
        const unsigned short* __restrict__ A,    // o bf16  [1024][2304]
        const unsigned short* __restrict__ Bt,   // W1T bf16 [512][2304]
        float*       __restrict__ hp)            // [2][1024][512] partials
{
    __shared__ unsigned short lds[2][2][64 * 64];   // [buf][A/B]

    const int t  = threadIdx.x;
    const int m0 = blockIdx.y * 64;
    const int n0 = blockIdx.x * 64;
    const int kz = blockIdx.z;
    const int kbase = kz * KSPLIT_HALF;

    const int w  = t >> 6, l = t & 63;
    const int wr = w >> 1, wc = w & 1;
    const int lr = l & 31;
    const int hi = l >> 5;
    const int sw = lr & 7;

    const int s_row0 = t >> 3;
    const int s_row1 = 32 + (t >> 3);
    const int s_slot = t & 7;

    const unsigned short* a_p0 = A  + (size_t)(m0 + s_row0) * K3H + kbase + s_slot * 8;
    const unsigned short* a_p1 = A  + (size_t)(m0 + s_row1) * K3H + kbase + s_slot * 8;
    const unsigned short* b_p0 = Bt + (size_t)(n0 + s_row0) * K3H + kbase + s_slot * 8;
    const unsigned short* b_p1 = Bt + (size_t)(n0 + s_row1) * K3H + kbase + s_slot * 8;

    const int w_idx0 = s_row0 * 64 + ((s_slot ^ (s_row0 & 7)) * 8);
    const int w_idx1 = s_row1 * 64 + ((s_slot ^ (s_row1 & 7)) * 8);

    f32x16 acc = {0.f,0.f,0.f,0.f,0.f,0.f,0.f,0.f,
                  0.f,0.f,0.f,0.f,0.f,0.f,0.f,0.f};

    ushort8x ra0 = *(const ushort8x*)(a_p0);
    ushort8x ra1 = *(const ushort8x*)(a_p1);
    ushort8x rb0 = *(const ushort8x*)(b_p0);
    ushort8x rb1 = *(const ushort8x*)(b_p1);
    *(ushort8x*)&lds[0][0][w_idx0] = ra0;
    *(ushort8x*)&lds[0][0][w_idx1] = ra1;
    *(ushort8x*)&lds[0][1][w_idx0] = rb0;
    *(ushort8x*)&lds[0][1][w_idx1] = rb1;
    __syncthreads();

    const int NT = KSPLIT_HALF / 64;   // 18
    int cur = 0;
    const int a_frag_row = (wr * 32 + lr) * 64;
    const int b_frag_row = (wc * 32 + lr) * 64;

    for (int step = 0; step < NT; ++step) {
        if (step + 1 < NT) {
            const size_t koff = (size_t)(step + 1) * 64;
            ra0 = *(const ushort8x*)(a_p0 + koff);
            ra1 = *(const ushort8x*)(a_p1 + koff);
            rb0 = *(const ushort8x*)(b_p0 + koff);
            rb1 = *(const ushort8x*)(b_p1 + koff);
        }

        const unsigned short* As = lds[cur][0];
        const unsigned short* Bs = lds[cur][1];
        #pragma unroll
        for (int kk = 0; kk < 64; kk += 16) {
            const int ks = (kk >> 3) + hi;
            bf16x8 af = *(const bf16x8*)&As[a_frag_row + ((ks ^ sw) * 8)];
            bf16x8 bf = *(const bf16x8*)&Bs[b_frag_row + ((ks ^ sw) * 8)];
            acc = __builtin_amdgcn_mfma_f32_32x32x16_bf16(af, bf, acc, 0, 0, 0);
        }
        __syncthreads();

        if (step + 1 < NT) {
            const int nb = cur ^ 1;
            *(ushort8x*)&lds[nb][0][w_idx0] = ra0;
            *(ushort8x*)&lds[nb][0][w_idx1] = ra1;
            *(ushort8x*)&lds[nb][1][w_idx0] = rb0;
            *(ushort8x*)&lds[nb][1][w_idx1] = rb1;
            __syncthreads();
            cur = nb;
        }
    }

    float* out = hp + (size_t)kz * B_SZ * HID;
    const int col = n0 + wc * 32 + lr;
    #pragma unroll
    for (int r = 0; r < 16; ++r) {
        int row = (r & 3) + 8 * (r >> 2) + 4 * hi;
        out[(size_t)(m0 + wr * 32 + row) * HID + col] = acc[r];
    }
}

// ---------------------------------------------------------------------------
// Kernel 3: out = relu(hp0 + hp1 + b1) @ W2 + b2.
// Grid 256 x 256 threads; wave w handles batch row blockIdx*4 + w.
// ---------------------------------------------------------------------------
__global__ __launch_bounds__(256) void mlp2_kernel(
        const float* __restrict__ hp,    // [2][1024][512]
        const float* __restrict__ b1,    // [512]
        const float* __restrict__ W2,    // [512][3]
        const float* __restrict__ b2,    // [3]
        float*       __restrict__ out)   // [1024][3]
{
    const int w = threadIdx.x >> 6;
    const int l = threadIdx.x & 63;
    const int b = blockIdx.x * 4 + w;

    const float* h0 = hp + (size_t)b * HID;
    const float* h1 = hp + (size_t)B_SZ * HID + (size_t)b * HID;

    float a0 = 0.f, a1 = 0.f, a2 = 0.f;
    #pragma unroll
    for (int kk = 0; kk < HID; kk += 64) {
        int k = kk + l;
        float hv = fmaxf(h0[k] + h1[k] + b1[k], 0.f);
        a0 += hv * W2[k * 3 + 0];
        a1 += hv * W2[k * 3 + 1];
        a2 += hv * W2[k * 3 + 2];
    }
    #pragma unroll
    for (int off = 32; off > 0; off >>= 1) {
        a0 += __shfl_down(a0, off);
        a1 += __shfl_down(a1, off);
        a2 += __shfl_down(a2, off);
    }
    if (l == 0) {
        out[b * 3 + 0] = a0 + b2[0];
        out[b * 3 + 1] = a1 + b2[1];
        out[b * 3 + 2] = a2 + b2[2];
    }
}

extern "C" void kernel_launch(void* const* d_in, const int* in_sizes, int n_in,
                              void* d_out, int out_size, void* d_ws, size_t ws_size,
                              hipStream_t stream) {
    const float* emb = (const float*)d_in[0];
    const int*   men = (const int*)  d_in[1];
    const float* W1  = (const float*)d_in[2];
    const float* b1  = (const float*)d_in[3];
    const float* W2  = (const float*)d_in[4];
    const float* b2  = (const float*)d_in[5];
    float* out = (float*)d_out;

    // ws layout:
    //   o_bf16 : 1024*2304*2 = 4718592 B
    //   W1T    :  512*2304*2 = 2359296 B
    //   hp     : 2*1024*512*4 = 4194304 B
    unsigned short* o_bf = (unsigned short*)d_ws;
    unsigned short* w1t  = o_bf + (size_t)B_SZ * K3H;
    float*          hp   = (float*)(w1t + (size_t)HID * K3H);

    pool_tr_kernel<<<POOL_BLKS + 288, 64, 0, stream>>>(emb, men, W1, o_bf, w1t);
    mlp1_kernel<<<dim3(8, 16, 2), 256, 0, stream>>>(o_bf, w1t, hp);
    mlp2_kernel<<<256, 256, 0, stream>>>(hp, b1, W2, b2, out);
}

// Round 6
// 185.769 us; speedup vs baseline: 1.0716x; 1.0716x over previous
//
#include <hip/hip_runtime.h>
#include <hip/hip_bf16.h>

#define B_SZ 1024
#define S_SZ 512
#define H_SZ 768
#define K3H  2304   // 3*H
#define HID  512
#define NC   3
#define KSPLIT_HALF 1152

typedef __attribute__((ext_vector_type(8)))  __bf16         bf16x8;
typedef __attribute__((ext_vector_type(16))) float          f32x16;
typedef __attribute__((ext_vector_type(4)))  float          f32x4;
typedef __attribute__((ext_vector_type(8)))  unsigned short ushort8x;

__device__ __forceinline__ unsigned short f2bf(float f) {
    unsigned u = __builtin_bit_cast(unsigned, f);
    unsigned r = (u + 0x7fffu + ((u >> 16) & 1u)) >> 16;
    return (unsigned short)r;
}

// ---------------------------------------------------------------------------
// Kernel 1 (merged): blocks [0,1024) = masked-mean pool (one 192-thread
// block per batch row; thread t owns float4 column t). Blocks [1024,1312) =
// W1 f32->bf16 transpose riding under the pool's memory shadow.
// Gather loop: unroll-8, nontemporal loads (read-once stream, 8 independent
// 16B requests in flight per lane for max memory-level parallelism).
// ---------------------------------------------------------------------------
__global__ __launch_bounds__(192) void pool_tr_kernel(
        const float* __restrict__ emb,          // [B,S,H] f32
        const int*   __restrict__ men,          // [B,S]
        const float* __restrict__ W1,           // [2304][512] f32
        unsigned short* __restrict__ o,         // [B,3H] bf16
        unsigned short* __restrict__ Bt)        // W1T [512][2304] bf16
{
    const int t = threadIdx.x;

    if (blockIdx.x >= B_SZ) {
        // ---- transpose path: 64x64 tiles, 36 k-tiles x 8 n-tiles = 288 ----
        __shared__ unsigned short tile[64][65];
        const int bt = blockIdx.x - B_SZ;
        const int kb = (bt >> 3) * 64;
        const int nb = (bt & 7) * 64;
        for (int i = t; i < 4096; i += 192) {
            int r = i >> 6, c = i & 63;
            tile[r][c] = f2bf(W1[(size_t)(kb + r) * HID + nb + c]);
        }
        __syncthreads();
        for (int i = t; i < 4096; i += 192) {
            int rr = i >> 6, cc = i & 63;
            Bt[(size_t)(nb + rr) * K3H + kb + cc] = tile[cc][rr];
        }
        return;
    }

    // ---- pool path ----
    const int b = blockIdx.x;
    __shared__ unsigned short sel[S_SZ];        // s | (tag<<12)
    __shared__ int nsel_sh;
    __shared__ int cnt[3];

    if (t < 64) {
        int basep = 0;
        int c0 = 0, c1 = 0, c2 = 0;
        const unsigned long long lt = (1ull << t) - 1ull;
        #pragma unroll
        for (int ch = 0; ch < 8; ++ch) {
            int s = ch * 64 + t;
            int m = men[(size_t)b * S_SZ + s];
            unsigned long long k2 = __ballot(m == 2);
            unsigned long long k3 = __ballot(m == 3);
            unsigned long long k4 = __ballot(m == 4);
            unsigned long long pk = k2 | k3 | k4;
            int pos = basep + __popcll(pk & lt);
            if (m >= 2) sel[pos] = (unsigned short)(s | ((m - 2) << 12));
            basep += __popcll(pk);
            c0 += __popcll(k2);
            c1 += __popcll(k3);
            c2 += __popcll(k4);
        }
        if (t == 0) { nsel_sh = basep; cnt[0] = c0; cnt[1] = c1; cnt[2] = c2; }
    }
    __syncthreads();

    const int ns = nsel_sh;
    f32x4 a0 = {0.f,0.f,0.f,0.f}, a1 = {0.f,0.f,0.f,0.f}, a2 = {0.f,0.f,0.f,0.f};
    const f32x4* base =
        reinterpret_cast<const f32x4*>(emb + (size_t)b * S_SZ * H_SZ) + t;

    #define ACCUM(E, V) do {                                             \
        int tg_ = (E) >> 12;                                             \
        if (tg_ == 0)      { a0 += (V); }                                \
        else if (tg_ == 1) { a1 += (V); }                                \
        else               { a2 += (V); }                                \
    } while (0)

    int i = 0;
    for (; i + 8 <= ns; i += 8) {
        int e0 = sel[i],   e1 = sel[i+1], e2 = sel[i+2], e3 = sel[i+3];
        int e4 = sel[i+4], e5 = sel[i+5], e6 = sel[i+6], e7 = sel[i+7];
        f32x4 v0 = __builtin_nontemporal_load(base + (e0 & 0x1ff) * 192);
        f32x4 v1 = __builtin_nontemporal_load(base + (e1 & 0x1ff) * 192);
        f32x4 v2 = __builtin_nontemporal_load(base + (e2 & 0x1ff) * 192);
        f32x4 v3 = __builtin_nontemporal_load(base + (e3 & 0x1ff) * 192);
        f32x4 v4 = __builtin_nontemporal_load(base + (e4 & 0x1ff) * 192);
        f32x4 v5 = __builtin_nontemporal_load(base + (e5 & 0x1ff) * 192);
        f32x4 v6 = __builtin_nontemporal_load(base + (e6 & 0x1ff) * 192);
        f32x4 v7 = __builtin_nontemporal_load(base + (e7 & 0x1ff) * 192);
        ACCUM(e0, v0); ACCUM(e1, v1); ACCUM(e2, v2); ACCUM(e3, v3);
        ACCUM(e4, v4); ACCUM(e5, v5); ACCUM(e6, v6); ACCUM(e7, v7);
    }
    for (; i + 4 <= ns; i += 4) {
        int e0 = sel[i], e1 = sel[i+1], e2 = sel[i+2], e3 = sel[i+3];
        f32x4 v0 = __builtin_nontemporal_load(base + (e0 & 0x1ff) * 192);
        f32x4 v1 = __builtin_nontemporal_load(base + (e1 & 0x1ff) * 192);
        f32x4 v2 = __builtin_nontemporal_load(base + (e2 & 0x1ff) * 192);
        f32x4 v3 = __builtin_nontemporal_load(base + (e3 & 0x1ff) * 192);
        ACCUM(e0, v0); ACCUM(e1, v1); ACCUM(e2, v2); ACCUM(e3, v3);
    }
    for (; i < ns; ++i) {
        int e = sel[i];
        f32x4 v = __builtin_nontemporal_load(base + (e & 0x1ff) * 192);
        ACCUM(e, v);
    }
    #undef ACCUM

    const float r0 = 1.f / (float)cnt[0];
    const float r1 = 1.f / (float)cnt[1];
    const float r2 = 1.f / (float)cnt[2];

    unsigned short* op = o + (size_t)b * K3H;
    ushort4 w0 = { f2bf(a0.x*r0), f2bf(a0.y*r0), f2bf(a0.z*r0), f2bf(a0.w*r0) };
    ushort4 w1 = { f2bf(a1.x*r1), f2bf(a1.y*r1), f2bf(a1.z*r1), f2bf(a1.w*r1) };
    ushort4 w2 = { f2bf(a2.x*r2), f2bf(a2.y*r2), f2bf(a2.z*r2), f2bf(a2.w*r2) };
    *reinterpret_cast<ushort4*>(op + 0 * H_SZ + t * 4) = w0;
    *reinterpret_cast<ushort4*>(op + 1 * H_SZ + t * 4) = w1;
    *reinterpret_cast<ushort4*>(op + 2 * H_SZ + t * 4) = w2;
}

// ---------------------------------------------------------------------------
// Kernel 2: partial GEMM  hp[kz] = o @ W1T  over k-slice kz (no bias/relu).
// 64x64 tile, BK=64, 4 waves (2x2 of 32x32 mfma_f32_32x32x16_bf16),
// 2-phase reg-staged double buffer, XOR-swizzled LDS.
// Grid (8, 16, 2) = 256 blocks, 18 K-steps per block.
// ---------------------------------------------------------------------------
__global__ __launch_bounds__(256) void mlp1_kernel(
        const unsigned short* __restrict__ A,    // o bf16  [1024][2304]
        const unsigned short* __restrict__ Bt,   // W1T bf16 [512][2304]
        float*       __restrict__ hp)            // [2][1024][512] partials
{
    __shared__ unsigned short lds[2][2][64 * 64];   // [buf][A/B]

    const int t  = threadIdx.x;
    const int m0 = blockIdx.y * 64;
    const int n0 = blockIdx.x * 64;
    const int kz = blockIdx.z;
    const int kbase = kz * KSPLIT_HALF;

    const int w  = t >> 6, l = t & 63;
    const int wr = w >> 1, wc = w & 1;
    const int lr = l & 31;
    const int hi = l >> 5;
    const int sw = lr & 7;

    const int s_row0 = t >> 3;
    const int s_row1 = 32 + (t >> 3);
    const int s_slot = t & 7;

    const unsigned short* a_p0 = A  + (size_t)(m0 + s_row0) * K3H + kbase + s_slot * 8;
    const unsigned short* a_p1 = A  + (size_t)(m0 + s_row1) * K3H + kbase + s_slot * 8;
    const unsigned short* b_p0 = Bt + (size_t)(n0 + s_row0) * K3H + kbase + s_slot * 8;
    const unsigned short* b_p1 = Bt + (size_t)(n0 + s_row1) * K3H + kbase + s_slot * 8;

    const int w_idx0 = s_row0 * 64 + ((s_slot ^ (s_row0 & 7)) * 8);
    const int w_idx1 = s_row1 * 64 + ((s_slot ^ (s_row1 & 7)) * 8);

    f32x16 acc = {0.f,0.f,0.f,0.f,0.f,0.f,0.f,0.f,
                  0.f,0.f,0.f,0.f,0.f,0.f,0.f,0.f};

    ushort8x ra0 = *(const ushort8x*)(a_p0);
    ushort8x ra1 = *(const ushort8x*)(a_p1);
    ushort8x rb0 = *(const ushort8x*)(b_p0);
    ushort8x rb1 = *(const ushort8x*)(b_p1);
    *(ushort8x*)&lds[0][0][w_idx0] = ra0;
    *(ushort8x*)&lds[0][0][w_idx1] = ra1;
    *(ushort8x*)&lds[0][1][w_idx0] = rb0;
    *(ushort8x*)&lds[0][1][w_idx1] = rb1;
    __syncthreads();

    const int NT = KSPLIT_HALF / 64;   // 18
    int cur = 0;
    const int a_frag_row = (wr * 32 + lr) * 64;
    const int b_frag_row = (wc * 32 + lr) * 64;

    for (int step = 0; step < NT; ++step) {
        if (step + 1 < NT) {
            const size_t koff = (size_t)(step + 1) * 64;
            ra0 = *(const ushort8x*)(a_p0 + koff);
            ra1 = *(const ushort8x*)(a_p1 + koff);
            rb0 = *(const ushort8x*)(b_p0 + koff);
            rb1 = *(const ushort8x*)(b_p1 + koff);
        }

        const unsigned short* As = lds[cur][0];
        const unsigned short* Bs = lds[cur][1];
        #pragma unroll
        for (int kk = 0; kk < 64; kk += 16) {
            const int ks = (kk >> 3) + hi;
            bf16x8 af = *(const bf16x8*)&As[a_frag_row + ((ks ^ sw) * 8)];
            bf16x8 bf = *(const bf16x8*)&Bs[b_frag_row + ((ks ^ sw) * 8)];
            acc = __builtin_amdgcn_mfma_f32_32x32x16_bf16(af, bf, acc, 0, 0, 0);
        }
        __syncthreads();

        if (step + 1 < NT) {
            const int nb = cur ^ 1;
            *(ushort8x*)&lds[nb][0][w_idx0] = ra0;
            *(ushort8x*)&lds[nb][0][w_idx1] = ra1;
            *(ushort8x*)&lds[nb][1][w_idx0] = rb0;
            *(ushort8x*)&lds[nb][1][w_idx1] = rb1;
            __syncthreads();
            cur = nb;
        }
    }

    float* out = hp + (size_t)kz * B_SZ * HID;
    const int col = n0 + wc * 32 + lr;
    #pragma unroll
    for (int r = 0; r < 16; ++r) {
        int row = (r & 3) + 8 * (r >> 2) + 4 * hi;
        out[(size_t)(m0 + wr * 32 + row) * HID + col] = acc[r];
    }
}

// ---------------------------------------------------------------------------
// Kernel 3: out = relu(hp0 + hp1 + b1) @ W2 + b2.
// Grid 256 x 256 threads; wave w handles batch row blockIdx*4 + w.
// ---------------------------------------------------------------------------
__global__ __launch_bounds__(256) void mlp2_kernel(
        const float* __restrict__ hp,    // [2][1024][512]
        const float* __restrict__ b1,    // [512]
        const float* __restrict__ W2,    // [512][3]
        const float* __restrict__ b2,    // [3]
        float*       __restrict__ out)   // [1024][3]
{
    const int w = threadIdx.x >> 6;
    const int l = threadIdx.x & 63;
    const int b = blockIdx.x * 4 + w;

    const float* h0 = hp + (size_t)b * HID;
    const float* h1 = hp + (size_t)B_SZ * HID + (size_t)b * HID;

    float a0 = 0.f, a1 = 0.f, a2 = 0.f;
    #pragma unroll
    for (int kk = 0; kk < HID; kk += 64) {
        int k = kk + l;
        float hv = fmaxf(h0[k] + h1[k] + b1[k], 0.f);
        a0 += hv * W2[k * 3 + 0];
        a1 += hv * W2[k * 3 + 1];
        a2 += hv * W2[k * 3 + 2];
    }
    #pragma unroll
    for (int off = 32; off > 0; off >>= 1) {
        a0 += __shfl_down(a0, off);
        a1 += __shfl_down(a1, off);
        a2 += __shfl_down(a2, off);
    }
    if (l == 0) {
        out[b * 3 + 0] = a0 + b2[0];
        out[b * 3 + 1] = a1 + b2[1];
        out[b * 3 + 2] = a2 + b2[2];
    }
}

extern "C" void kernel_launch(void* const* d_in, const int* in_sizes, int n_in,
                              void* d_out, int out_size, void* d_ws, size_t ws_size,
                              hipStream_t stream) {
    const float* emb = (const float*)d_in[0];
    const int*   men = (const int*)  d_in[1];
    const float* W1  = (const float*)d_in[2];
    const float* b1  = (const float*)d_in[3];
    const float* W2  = (const float*)d_in[4];
    const float* b2  = (const float*)d_in[5];
    float* out = (float*)d_out;

    // ws layout:
    //   o_bf16 : 1024*2304*2 = 4718592 B
    //   W1T    :  512*2304*2 = 2359296 B
    //   hp     : 2*1024*512*4 = 4194304 B
    unsigned short* o_bf = (unsigned short*)d_ws;
    unsigned short* w1t  = o_bf + (size_t)B_SZ * K3H;
    float*          hp   = (float*)(w1t + (size_t)HID * K3H);

    pool_tr_kernel<<<B_SZ + 288, 192, 0, stream>>>(emb, men, W1, o_bf, w1t);
    mlp1_kernel<<<dim3(8, 16, 2), 256, 0, stream>>>(o_bf, w1t, hp);
    mlp2_kernel<<<256, 256, 0, stream>>>(hp, b1, W2, b2, out);
}